// Round 1
// baseline (629.347 us; speedup 1.0000x reference)
//
#include <hip/hip_runtime.h>
#include <hip/hip_bf16.h>
#include <math.h>

#define NN 10000

typedef __bf16 bf16;
typedef bf16 bf16x8 __attribute__((ext_vector_type(8)));
typedef float f32x4 __attribute__((ext_vector_type(4)));

__device__ __forceinline__ float wave_sum64(float v) {
#pragma unroll
  for (int m = 32; m >= 1; m >>= 1) v += __shfl_xor(v, m, 64);
  return v;
}

// ---------------------------------------------------------------- prep
// transpose small weights to [n][k] bf16, pack qkv biases, freqs, lam_full
__global__ void prep_kernel(const float* __restrict__ w1, const float* __restrict__ w2,
                            const float* __restrict__ wq1, const float* __restrict__ wk1,
                            const float* __restrict__ wq2, const float* __restrict__ wk2,
                            const float* __restrict__ wvw,
                            const float* __restrict__ bq1, const float* __restrict__ bk1,
                            const float* __restrict__ bq2, const float* __restrict__ bk2,
                            const float* __restrict__ bvv,
                            const float* __restrict__ lq1, const float* __restrict__ lk1,
                            const float* __restrict__ lq2, const float* __restrict__ lk2,
                            const float* __restrict__ freq_deltas, const float* __restrict__ freq_bias,
                            bf16* __restrict__ w1T, bf16* __restrict__ w2T, bf16* __restrict__ qkvT,
                            float* __restrict__ bqkv, float* __restrict__ freqs, float* __restrict__ lamb) {
  int tid = blockIdx.x * blockDim.x + threadIdx.x;
  int nthr = gridDim.x * blockDim.x;
  for (int i = tid; i < 512 * 128; i += nthr) {
    int o = i >> 9, k = i & 511;            // w1T[128][512]
    w1T[i] = (bf16)w1[k * 128 + o];
  }
  for (int i = tid; i < 64 * 128; i += nthr) {
    int o = i >> 7, k = i & 127;            // w2T[64][128]
    w2T[i] = (bf16)w2[k * 64 + o];
  }
  for (int i = tid; i < 320 * 64; i += nthr) {
    int r = i >> 6, k = i & 63;             // qkvT[320][64]
    const float* W = (r < 64) ? wq1 : (r < 128) ? wk1 : (r < 192) ? wq2 : (r < 256) ? wk2 : wvw;
    qkvT[i] = (bf16)W[k * 64 + (r & 63)];
  }
  for (int i = tid; i < 320; i += nthr) {
    const float* B = (i < 64) ? bq1 : (i < 128) ? bk1 : (i < 192) ? bq2 : (i < 256) ? bk2 : bvv;
    bqkv[i] = B[i & 63];
  }
  if (blockIdx.x == 0) {
    if (threadIdx.x == 0) {
      float acc = freq_bias[0];
      for (int f = 0; f < 16; f++) {
        acc += log1pf(expf(freq_deltas[f])) + 0.25f;       // softplus + DMIN, cumsum
        freqs[f] = 50.0f * tanhf(acc * (1.0f / 50.0f));    // OMEGA*tanh(x/OMEGA)
      }
    }
    if (threadIdx.x >= 64 && threadIdx.x < 128) {
      int l = threadIdx.x - 64;
      float s1 = wave_sum64(lq1[l] * lk1[l]);
      float s2 = wave_sum64(lq2[l] * lk2[l]);
      if (l == 0) lamb[0] = expf(s1) - expf(s2) + 0.2f;    // lam_full (lam_init=0.2)
    }
  }
}

// ---------------------------------------------------------------- new_e
__global__ void newe_kernel(const float* __restrict__ e, const float* __restrict__ rw,
                            const float* __restrict__ rb, const float* __restrict__ aw,
                            const float* __restrict__ freqs, float* __restrict__ newe) {
  int n = blockIdx.x * blockDim.x + threadIdx.x;
  if (n >= NN) return;
  float fr[16];
#pragma unroll
  for (int f = 0; f < 16; f++) fr[f] = freqs[f];
  float ev = e[n], p = 1.0f, acc = 0.0f;
  for (int k = 0; k < 10; k++) {
    p *= ev;
    float s = rb[k] + rw[k * 33];
#pragma unroll
    for (int f = 0; f < 16; f++) {
      float ph = p * fr[f];
      s += 0.25f * (__sinf(ph) * rw[k * 33 + 1 + f] + __cosf(ph) * rw[k * 33 + 17 + f]);
    }
    acc += s * aw[k];
  }
  newe[n] = acc;
}

// ---------------------------------------------------------------- G1: t1b = bf16(relu(x@W1 + b1))
__global__ __launch_bounds__(256) void g1_kernel(const float* __restrict__ x, const bf16* __restrict__ w1T,
                                                 const float* __restrict__ b1, bf16* __restrict__ t1b) {
  __shared__ bf16 la[64][40];
  __shared__ bf16 lb[128][40];
  const int bm = blockIdx.x * 64;
  const int lane = threadIdx.x & 63, wvid = threadIdx.x >> 6;
  const int am = threadIdx.x >> 2, aseg = (threadIdx.x & 3) * 8;
  const int arow = bm + am;
  f32x4 acc[8] = {};
  float4 aLo, aHi;
  uint4 bChunk[2];
  auto fetchAll = [&](int k0) {
    if (arow < NN) {
      const float4* p = (const float4*)(x + (size_t)arow * 512 + k0 + aseg);
      aLo = p[0]; aHi = p[1];
    } else {
      aLo = make_float4(0.f, 0.f, 0.f, 0.f); aHi = aLo;
    }
#pragma unroll
    for (int r = 0; r < 2; r++) {
      int slot = threadIdx.x * 2 + r;
      int n = slot >> 2, seg = (slot & 3) * 8;
      bChunk[r] = *(const uint4*)(w1T + n * 512 + k0 + seg);
    }
  };
  auto store = [&]() {
    union { uint4 v; bf16 b[8]; } pk;
    float av[8] = {aLo.x, aLo.y, aLo.z, aLo.w, aHi.x, aHi.y, aHi.z, aHi.w};
#pragma unroll
    for (int t = 0; t < 8; t++) pk.b[t] = (bf16)av[t];
    *(uint4*)&la[am][aseg] = pk.v;
#pragma unroll
    for (int r = 0; r < 2; r++) {
      int slot = threadIdx.x * 2 + r;
      int n = slot >> 2, seg = (slot & 3) * 8;
      *(uint4*)&lb[n][seg] = bChunk[r];
    }
  };
  fetchAll(0);
  for (int k0 = 0; k0 < 512; k0 += 32) {
    store();
    if (k0 + 32 < 512) fetchAll(k0 + 32);
    __syncthreads();
    bf16x8 af = *(const bf16x8*)&la[wvid * 16 + (lane & 15)][(lane >> 4) * 8];
#pragma unroll
    for (int s = 0; s < 8; s++) {
      bf16x8 bfr = *(const bf16x8*)&lb[s * 16 + (lane & 15)][(lane >> 4) * 8];
      acc[s] = __builtin_amdgcn_mfma_f32_16x16x32_bf16(af, bfr, acc[s], 0, 0, 0);
    }
    __syncthreads();
  }
#pragma unroll
  for (int s = 0; s < 8; s++) {
    int col = s * 16 + (lane & 15);
    float bvv = b1[col];
#pragma unroll
    for (int r = 0; r < 4; r++) {
      int row = bm + wvid * 16 + (lane >> 4) * 4 + r;
      if (row < NN) {
        float v = acc[s][r] + bvv;
        t1b[(size_t)row * 128 + col] = (bf16)(v > 0.f ? v : 0.f);
      }
    }
  }
}

// ---------------------------------------------------------------- G2: h = t1b@W2 + b2 (f32) ; hT bf16
__global__ __launch_bounds__(256) void g2_kernel(const bf16* __restrict__ t1b, const bf16* __restrict__ w2T,
                                                 const float* __restrict__ b2, float* __restrict__ h,
                                                 bf16* __restrict__ hT) {
  __shared__ bf16 la[64][72];
  __shared__ bf16 lb[64][72];
  const int bm = blockIdx.x * 64;
  const int lane = threadIdx.x & 63, wvid = threadIdx.x >> 6;
  f32x4 acc[4] = {};
  for (int k0 = 0; k0 < 128; k0 += 64) {
#pragma unroll
    for (int r = 0; r < 2; r++) {
      int slot = threadIdx.x * 2 + r;
      int m = slot >> 3, seg = (slot & 7) * 8;
      int row = bm + m;
      uint4 val = make_uint4(0u, 0u, 0u, 0u);
      if (row < NN) val = *(const uint4*)(t1b + (size_t)row * 128 + k0 + seg);
      *(uint4*)&la[m][seg] = val;
      *(uint4*)&lb[m][seg] = *(const uint4*)(w2T + m * 128 + k0 + seg);
    }
    __syncthreads();
#pragma unroll
    for (int ks = 0; ks < 2; ks++) {
      bf16x8 af = *(const bf16x8*)&la[wvid * 16 + (lane & 15)][ks * 32 + (lane >> 4) * 8];
#pragma unroll
      for (int s = 0; s < 4; s++) {
        bf16x8 bfr = *(const bf16x8*)&lb[s * 16 + (lane & 15)][ks * 32 + (lane >> 4) * 8];
        acc[s] = __builtin_amdgcn_mfma_f32_16x16x32_bf16(af, bfr, acc[s], 0, 0, 0);
      }
    }
    __syncthreads();
  }
#pragma unroll
  for (int s = 0; s < 4; s++) {
    int col = s * 16 + (lane & 15);
    float bvv = b2[col];
#pragma unroll
    for (int r = 0; r < 4; r++) {
      int row = bm + wvid * 16 + (lane >> 4) * 4 + r;
      if (row < NN) {
        float v = acc[s][r] + bvv;
        h[(size_t)row * 64 + col] = v;
        hT[(size_t)col * NN + row] = (bf16)v;
      }
    }
  }
}

// ---------------------------------------------------------------- mh = LN(h) (bf16)
__global__ __launch_bounds__(256) void mhln_kernel(const float* __restrict__ h, const float* __restrict__ g,
                                                   const float* __restrict__ b, bf16* __restrict__ mh) {
  int row = blockIdx.x * 4 + (threadIdx.x >> 6);
  int lane = threadIdx.x & 63;
  if (row >= NN) return;
  float v = h[(size_t)row * 64 + lane];
  float m = wave_sum64(v) * (1.0f / 64.0f);
  float d = v - m;
  float var = wave_sum64(d * d) * (1.0f / 64.0f);
  mh[(size_t)row * 64 + lane] = (bf16)(g[lane] * d * rsqrtf(var + 1e-5f) + b[lane]);
}

// ---------------------------------------------------------------- QKV: mh @ [wq1|wk1|wq2|wk2|wv] + b
__global__ __launch_bounds__(256) void qkv_kernel(const bf16* __restrict__ mh, const bf16* __restrict__ qkvT,
                                                  const float* __restrict__ bqkv,
                                                  bf16* __restrict__ qq, bf16* __restrict__ kv) {
  __shared__ bf16 la[64][72];
  __shared__ bf16 lb[320][72];
  const int bm = blockIdx.x * 64;
  const int lane = threadIdx.x & 63, wvid = threadIdx.x >> 6;
#pragma unroll
  for (int r = 0; r < 2; r++) {
    int slot = threadIdx.x * 2 + r;
    int m = slot >> 3, seg = (slot & 7) * 8;
    int row = bm + m;
    uint4 val = make_uint4(0u, 0u, 0u, 0u);
    if (row < NN) val = *(const uint4*)(mh + (size_t)row * 64 + seg);
    *(uint4*)&la[m][seg] = val;
  }
#pragma unroll
  for (int r = 0; r < 10; r++) {
    int slot = threadIdx.x * 10 + r;
    int n = slot >> 3, seg = (slot & 7) * 8;
    *(uint4*)&lb[n][seg] = *(const uint4*)(qkvT + n * 64 + seg);
  }
  __syncthreads();
  f32x4 acc[20] = {};
#pragma unroll
  for (int ks = 0; ks < 2; ks++) {
    bf16x8 af = *(const bf16x8*)&la[wvid * 16 + (lane & 15)][ks * 32 + (lane >> 4) * 8];
#pragma unroll
    for (int s = 0; s < 20; s++) {
      bf16x8 bfr = *(const bf16x8*)&lb[s * 16 + (lane & 15)][ks * 32 + (lane >> 4) * 8];
      acc[s] = __builtin_amdgcn_mfma_f32_16x16x32_bf16(af, bfr, acc[s], 0, 0, 0);
    }
  }
#pragma unroll
  for (int s = 0; s < 20; s++) {
    int col = s * 16 + (lane & 15);
    float bvv = bqkv[col];
    bf16* dst; int dc, stride;
    if (col < 64)       { dst = qq; dc = col;       stride = 128; }  // q1
    else if (col < 128) { dst = kv; dc = col - 64;  stride = 192; }  // k1
    else if (col < 192) { dst = qq; dc = col - 64;  stride = 128; }  // q2
    else                { dst = kv; dc = col - 128; stride = 192; }  // k2 | v
#pragma unroll
    for (int r = 0; r < 4; r++) {
      int row = bm + wvid * 16 + (lane >> 4) * 4 + r;
      if (row < NN) dst[(size_t)row * stride + dc] = (bf16)(acc[s][r] + bvv);
    }
  }
}

// ---------------------------------------------------------------- R1: partial k1^T v, k2^T v
__global__ __launch_bounds__(256) void r1_kernel(const bf16* __restrict__ kv, float* __restrict__ part) {
  int b = blockIdx.x;
  int c1 = threadIdx.x & 63, grp = threadIdx.x >> 6;
  float a1[16] = {}, a2[16] = {};
  for (int i = b; i < NN; i += 64) {
    const bf16* rowp = kv + (size_t)i * 192;
    float k1 = (float)rowp[c1];
    float k2 = (float)rowp[64 + c1];
    float vv[16];
#pragma unroll
    for (int q = 0; q < 16; q++) vv[q] = (float)rowp[128 + grp * 16 + q];
#pragma unroll
    for (int q = 0; q < 16; q++) { a1[q] += k1 * vv[q]; a2[q] += k2 * vv[q]; }
  }
  float* p1 = part + ((size_t)(b * 2 + 0) * 64 + c1) * 64 + grp * 16;
  float* p2 = part + ((size_t)(b * 2 + 1) * 64 + c1) * 64 + grp * 16;
#pragma unroll
  for (int q = 0; q < 16; q++) { p1[q] = a1[q]; p2[q] = a2[q]; }
}

// ---------------------------------------------------------------- R2: reduce -> Bt[c][128] = [k1v^T | -lam*k2v^T]
__global__ void r2_kernel(const float* __restrict__ part, const float* __restrict__ lamb, bf16* __restrict__ Bt) {
  int idx = blockIdx.x * 256 + threadIdx.x;
  int mat = idx >> 12, rem = idx & 4095;
  int d = rem >> 6, c = rem & 63;
  float s = 0.f;
  for (int b = 0; b < 64; b++) s += part[(size_t)(b * 2 + mat) * 4096 + rem];
  float v = mat ? (-lamb[0] * s) : s;
  Bt[c * 128 + mat * 64 + d] = (bf16)v;
}

// ---------------------------------------------------------------- D: w_utxT[c][j] = new_e[j] * sum_i h[i,c]*u[i,j]
__global__ __launch_bounds__(256) void d_kernel(const float* __restrict__ u, const bf16* __restrict__ hT,
                                                const float* __restrict__ newe, bf16* __restrict__ wutxT) {
  __shared__ bf16 la[64][72];
  __shared__ bf16 lb[32][72];
  const int j0 = blockIdx.x * 32;
  const int lane = threadIdx.x & 63, wvid = threadIdx.x >> 6;
  const int jl = (threadIdx.x & 7) * 4;
  const int ipp = (threadIdx.x >> 3) * 2;
  const bool jin = (j0 + jl) < NN;
  f32x4 acc[2] = {};
  uint4 aChunk[2];
  float4 bLo, bHi;
  auto fetchAll = [&](int i0) {
#pragma unroll
    for (int r = 0; r < 2; r++) {
      int slot = threadIdx.x * 2 + r;
      int c = slot >> 3, seg = (slot & 7) * 8;
      int i = i0 + seg;
      if (i + 7 < NN) aChunk[r] = *(const uint4*)(hT + (size_t)c * NN + i);
      else {
        union { uint4 v; bf16 b[8]; } tu;
#pragma unroll
        for (int t = 0; t < 8; t++) tu.b[t] = (i + t < NN) ? hT[(size_t)c * NN + i + t] : (bf16)0.f;
        aChunk[r] = tu.v;
      }
    }
    bLo = make_float4(0.f, 0.f, 0.f, 0.f); bHi = bLo;
    if (jin) {
      int ia = i0 + ipp;
      if (ia < NN)     bLo = *(const float4*)(u + (size_t)ia * NN + j0 + jl);
      if (ia + 1 < NN) bHi = *(const float4*)(u + (size_t)(ia + 1) * NN + j0 + jl);
    }
  };
  auto store = [&]() {
#pragma unroll
    for (int r = 0; r < 2; r++) {
      int slot = threadIdx.x * 2 + r;
      int c = slot >> 3, seg = (slot & 7) * 8;
      *(uint4*)&la[c][seg] = aChunk[r];
    }
    float lov[4] = {bLo.x, bLo.y, bLo.z, bLo.w};
    float hiv[4] = {bHi.x, bHi.y, bHi.z, bHi.w};
#pragma unroll
    for (int t = 0; t < 4; t++) {
      union { unsigned w; bf16 b[2]; } pk;
      pk.b[0] = (bf16)lov[t];
      pk.b[1] = (bf16)hiv[t];
      *(unsigned*)&lb[jl + t][ipp] = pk.w;   // transpose: lb[j][i]
    }
  };
  fetchAll(0);
  for (int i0 = 0; i0 < NN; i0 += 64) {
    store();
    if (i0 + 64 < NN) fetchAll(i0 + 64);
    __syncthreads();
#pragma unroll
    for (int ks = 0; ks < 2; ks++) {
      bf16x8 af = *(const bf16x8*)&la[wvid * 16 + (lane & 15)][ks * 32 + (lane >> 4) * 8];
#pragma unroll
      for (int s = 0; s < 2; s++) {
        bf16x8 bfr = *(const bf16x8*)&lb[s * 16 + (lane & 15)][ks * 32 + (lane >> 4) * 8];
        acc[s] = __builtin_amdgcn_mfma_f32_16x16x32_bf16(af, bfr, acc[s], 0, 0, 0);
      }
    }
    __syncthreads();
  }
#pragma unroll
  for (int s = 0; s < 2; s++) {
    int j = j0 + s * 16 + (lane & 15);
    if (j < NN) {
      float ne = newe[j];
#pragma unroll
      for (int r = 0; r < 4; r++) {
        int c = wvid * 16 + (lane >> 4) * 4 + r;
        wutxT[(size_t)c * NN + j] = (bf16)(ne * acc[s][r]);
      }
    }
  }
}

// ---------------------------------------------------------------- E: h_fur = u @ w_utx
__global__ __launch_bounds__(256) void e_kernel(const float* __restrict__ u, const bf16* __restrict__ wutxT,
                                                float* __restrict__ h_fur) {
  __shared__ bf16 la[32][72];
  __shared__ bf16 lb[64][72];
  const int bm = blockIdx.x * 32;
  const int lane = threadIdx.x & 63, wvid = threadIdx.x >> 6;
  const int am = threadIdx.x >> 3, aseg = (threadIdx.x & 7) * 8;
  const int arow = bm + am;
  const int m0 = (wvid & 1) * 16, n0 = (wvid >> 1) * 32;
  f32x4 acc[2] = {};
  float av[8];
  uint4 bChunk[2];
  auto fetchAll = [&](int j0) {
    int j = j0 + aseg;
    if (arow < NN && j + 7 < NN) {
      const float4* p = (const float4*)(u + (size_t)arow * NN + j);
      float4 lo = p[0], hi = p[1];
      av[0] = lo.x; av[1] = lo.y; av[2] = lo.z; av[3] = lo.w;
      av[4] = hi.x; av[5] = hi.y; av[6] = hi.z; av[7] = hi.w;
    } else {
#pragma unroll
      for (int t = 0; t < 8; t++)
        av[t] = (arow < NN && j + t < NN) ? u[(size_t)arow * NN + j + t] : 0.f;
    }
#pragma unroll
    for (int r = 0; r < 2; r++) {
      int slot = threadIdx.x * 2 + r;
      int n = slot >> 3, seg = (slot & 7) * 8;
      int jj = j0 + seg;
      if (jj + 7 < NN) bChunk[r] = *(const uint4*)(wutxT + (size_t)n * NN + jj);
      else {
        union { uint4 v; bf16 b[8]; } tu;
#pragma unroll
        for (int t = 0; t < 8; t++) tu.b[t] = (jj + t < NN) ? wutxT[(size_t)n * NN + jj + t] : (bf16)0.f;
        bChunk[r] = tu.v;
      }
    }
  };
  auto store = [&]() {
    union { uint4 v; bf16 b[8]; } pk;
#pragma unroll
    for (int t = 0; t < 8; t++) pk.b[t] = (bf16)av[t];
    *(uint4*)&la[am][aseg] = pk.v;
#pragma unroll
    for (int r = 0; r < 2; r++) {
      int slot = threadIdx.x * 2 + r;
      int n = slot >> 3, seg = (slot & 7) * 8;
      *(uint4*)&lb[n][seg] = bChunk[r];
    }
  };
  fetchAll(0);
  for (int j0 = 0; j0 < NN; j0 += 64) {
    store();
    if (j0 + 64 < NN) fetchAll(j0 + 64);
    __syncthreads();
#pragma unroll
    for (int ks = 0; ks < 2; ks++) {
      bf16x8 af = *(const bf16x8*)&la[m0 + (lane & 15)][ks * 32 + (lane >> 4) * 8];
#pragma unroll
      for (int s = 0; s < 2; s++) {
        bf16x8 bfr = *(const bf16x8*)&lb[n0 + s * 16 + (lane & 15)][ks * 32 + (lane >> 4) * 8];
        acc[s] = __builtin_amdgcn_mfma_f32_16x16x32_bf16(af, bfr, acc[s], 0, 0, 0);
      }
    }
    __syncthreads();
  }
#pragma unroll
  for (int s = 0; s < 2; s++) {
    int col = n0 + s * 16 + (lane & 15);
#pragma unroll
    for (int r = 0; r < 4; r++) {
      int row = bm + m0 + (lane >> 4) * 4 + r;
      if (row < NN) h_fur[(size_t)row * 64 + col] = acc[s][r];
    }
  }
}

// ---------------------------------------------------------------- H: xa = qq@Bt ; LN ; *0.8 -> xan bf16
__global__ __launch_bounds__(256) void hattn_kernel(const bf16* __restrict__ qq, const bf16* __restrict__ Bt,
                                                    const float* __restrict__ g, const float* __restrict__ b,
                                                    bf16* __restrict__ xan) {
  __shared__ bf16 la[64][136];
  __shared__ bf16 lb[64][136];
  const int bm = blockIdx.x * 64;
  const int lane = threadIdx.x & 63, wvid = threadIdx.x >> 6;
#pragma unroll
  for (int r = 0; r < 4; r++) {
    int slot = threadIdx.x * 4 + r;
    int m = slot >> 4, seg = (slot & 15) * 8;
    int row = bm + m;
    uint4 val = make_uint4(0u, 0u, 0u, 0u);
    if (row < NN) val = *(const uint4*)(qq + (size_t)row * 128 + seg);
    *(uint4*)&la[m][seg] = val;
    *(uint4*)&lb[m][seg] = *(const uint4*)(Bt + m * 128 + seg);
  }
  __syncthreads();
  f32x4 acc[4] = {};
#pragma unroll
  for (int ks = 0; ks < 4; ks++) {
    bf16x8 af = *(const bf16x8*)&la[wvid * 16 + (lane & 15)][ks * 32 + (lane >> 4) * 8];
#pragma unroll
    for (int s = 0; s < 4; s++) {
      bf16x8 bfr = *(const bf16x8*)&lb[s * 16 + (lane & 15)][ks * 32 + (lane >> 4) * 8];
      acc[s] = __builtin_amdgcn_mfma_f32_16x16x32_bf16(af, bfr, acc[s], 0, 0, 0);
    }
  }
#pragma unroll
  for (int r = 0; r < 4; r++) {
    float psum = acc[0][r] + acc[1][r] + acc[2][r] + acc[3][r];
#pragma unroll
    for (int msk = 1; msk < 16; msk <<= 1) psum += __shfl_xor(psum, msk, 64);
    float mean = psum * (1.0f / 64.0f);
    float pvar = 0.f;
#pragma unroll
    for (int s = 0; s < 4; s++) { float dd = acc[s][r] - mean; pvar += dd * dd; }
#pragma unroll
    for (int msk = 1; msk < 16; msk <<= 1) pvar += __shfl_xor(pvar, msk, 64);
    float rsq = rsqrtf(pvar * (1.0f / 64.0f) + 1e-5f);
    int row = bm + wvid * 16 + (lane >> 4) * 4 + r;
    if (row < NN) {
#pragma unroll
      for (int s = 0; s < 4; s++) {
        int col = s * 16 + (lane & 15);
        float o = 0.8f * (g[col] * (acc[s][r] - mean) * rsq + b[col]);
        xan[(size_t)row * 64 + col] = (bf16)o;
      }
    }
  }
}

// ---------------------------------------------------------------- final: mha matvec + gate + FFN + residual
__global__ __launch_bounds__(256) void final_kernel(const float* __restrict__ h, const float* __restrict__ h_fur,
                                                    const bf16* __restrict__ xan,
                                                    const float* __restrict__ out_w, const float* __restrict__ out_b,
                                                    const float* __restrict__ gg, const float* __restrict__ gb,
                                                    const float* __restrict__ gw, const float* __restrict__ gbias,
                                                    const float* __restrict__ fg, const float* __restrict__ fb,
                                                    const float* __restrict__ fw1, const float* __restrict__ fb1,
                                                    const float* __restrict__ fw2, const float* __restrict__ fb2,
                                                    float* __restrict__ out) {
  __shared__ float s_ow[64][64];
  __shared__ float s_w1[64][64];
  __shared__ float s_w2[64][64];
  __shared__ float s_gw[192][3];
  __shared__ float s_row[4][64];
  const int lane = threadIdx.x & 63, wvid = threadIdx.x >> 6;
  for (int i = threadIdx.x; i < 4096; i += 256) {
    ((float*)s_ow)[i] = out_w[i];
    ((float*)s_w1)[i] = fw1[i];
    ((float*)s_w2)[i] = fw2[i];
  }
  for (int i = threadIdx.x; i < 576; i += 256) ((float*)s_gw)[i] = gw[i];
  const int row = blockIdx.x * 4 + wvid;
  float x_h = h[(size_t)row * 64 + lane];
  float x_f = h_fur[(size_t)row * 64 + lane];
  float x_a = (float)xan[(size_t)row * 64 + lane];
  s_row[wvid][lane] = x_a;
  __syncthreads();
  float mha = out_b[lane];
#pragma unroll 8
  for (int d = 0; d < 64; d++) mha += s_row[wvid][d] * s_ow[d][lane];
  // gate LN over 192
  float m3 = wave_sum64(x_h + mha + x_f) * (1.0f / 192.0f);
  float dh = x_h - m3, dm = mha - m3, df = x_f - m3;
  float v3 = wave_sum64(dh * dh + dm * dm + df * df) * (1.0f / 192.0f);
  float rs3 = rsqrtf(v3 + 1e-5f);
  float l0 = gg[lane] * dh * rs3 + gb[lane];
  float l1 = gg[64 + lane] * dm * rs3 + gb[64 + lane];
  float l2 = gg[128 + lane] * df * rs3 + gb[128 + lane];
  float p0 = l0 * s_gw[lane][0] + l1 * s_gw[64 + lane][0] + l2 * s_gw[128 + lane][0];
  float p1 = l0 * s_gw[lane][1] + l1 * s_gw[64 + lane][1] + l2 * s_gw[128 + lane][1];
  float p2 = l0 * s_gw[lane][2] + l1 * s_gw[64 + lane][2] + l2 * s_gw[128 + lane][2];
  p0 = wave_sum64(p0) + gbias[0];
  p1 = wave_sum64(p1) + gbias[1];
  p2 = wave_sum64(p2) + gbias[2];
  float mx = fmaxf(p0, fmaxf(p1, p2));
  float e0 = expf(p0 - mx), e1 = expf(p1 - mx), e2 = expf(p2 - mx);
  float inv = 1.0f / (e0 + e1 + e2);
  float mix = x_h * (e0 * inv) + mha * (e1 * inv) + x_f * (e2 * inv);
  // FFN
  float mf = wave_sum64(mix) * (1.0f / 64.0f);
  float dmx = mix - mf;
  float vf = wave_sum64(dmx * dmx) * (1.0f / 64.0f);
  float f = fg[lane] * dmx * rsqrtf(vf + 1e-5f) + fb[lane];
  __syncthreads();
  s_row[wvid][lane] = f;
  __syncthreads();
  float t1 = fb1[lane];
#pragma unroll 8
  for (int d = 0; d < 64; d++) t1 += s_row[wvid][d] * s_w1[d][lane];
  t1 = 0.5f * t1 * (1.0f + erff(t1 * 0.70710678118654752f));   // exact gelu
  __syncthreads();
  s_row[wvid][lane] = t1;
  __syncthreads();
  float f2 = fb2[lane];
#pragma unroll 8
  for (int d = 0; d < 64; d++) f2 += s_row[wvid][d] * s_w2[d][lane];
  out[(size_t)row * 64 + lane] = mix + f2;
}

// ================================================================ launch
extern "C" void kernel_launch(void* const* d_in, const int* in_sizes, int n_in,
                              void* d_out, int out_size, void* d_ws, size_t ws_size,
                              hipStream_t stream) {
  const float* e          = (const float*)d_in[0];
  const float* u          = (const float*)d_in[1];
  const float* x          = (const float*)d_in[2];
  const float* fe_w1      = (const float*)d_in[3];
  const float* fe_b1      = (const float*)d_in[4];
  const float* fe_w2      = (const float*)d_in[5];
  const float* fe_b2      = (const float*)d_in[6];
  const float* freq_deltas= (const float*)d_in[7];
  const float* freq_bias  = (const float*)d_in[8];
  const float* readout_w  = (const float*)d_in[9];
  const float* readout_b  = (const float*)d_in[10];
  const float* alpha_w    = (const float*)d_in[11];
  const float* mha_ln_g   = (const float*)d_in[12];
  const float* mha_ln_b   = (const float*)d_in[13];
  const float* wq1        = (const float*)d_in[14];
  const float* bq1        = (const float*)d_in[15];
  const float* wk1        = (const float*)d_in[16];
  const float* bk1        = (const float*)d_in[17];
  const float* wq2        = (const float*)d_in[18];
  const float* bq2        = (const float*)d_in[19];
  const float* wk2        = (const float*)d_in[20];
  const float* bk2        = (const float*)d_in[21];
  const float* wv_in      = (const float*)d_in[22];
  const float* bv_in      = (const float*)d_in[23];
  const float* lq1        = (const float*)d_in[24];
  const float* lk1        = (const float*)d_in[25];
  const float* lq2        = (const float*)d_in[26];
  const float* lk2        = (const float*)d_in[27];
  const float* attn_ln_g  = (const float*)d_in[28];
  const float* attn_ln_b  = (const float*)d_in[29];
  const float* out_w      = (const float*)d_in[30];
  const float* out_b      = (const float*)d_in[31];
  const float* gate_ln_g  = (const float*)d_in[32];
  const float* gate_ln_b  = (const float*)d_in[33];
  const float* gate_w     = (const float*)d_in[34];
  const float* gate_b     = (const float*)d_in[35];
  const float* ffn_ln_g   = (const float*)d_in[36];
  const float* ffn_ln_b   = (const float*)d_in[37];
  const float* ffn_w1     = (const float*)d_in[38];
  const float* ffn_b1     = (const float*)d_in[39];
  const float* ffn_w2     = (const float*)d_in[40];
  const float* ffn_b2     = (const float*)d_in[41];

  constexpr size_t OFF_H     = 0;                      // f32 N*64
  constexpr size_t OFF_T1B   = OFF_H     + 2560000;    // bf16 N*128
  constexpr size_t OFF_HT    = OFF_T1B   + 2560000;    // bf16 64*N
  constexpr size_t OFF_MH    = OFF_HT    + 1280000;    // bf16 N*64
  constexpr size_t OFF_QQ    = OFF_MH    + 1280000;    // bf16 N*128
  constexpr size_t OFF_KV    = OFF_QQ    + 2560000;    // bf16 N*192
  constexpr size_t OFF_WUTXT = OFF_KV    + 3840000;    // bf16 64*N
  constexpr size_t OFF_HFUR  = OFF_WUTXT + 1280000;    // f32 N*64
  constexpr size_t OFF_XAN   = OFF_HFUR  + 2560000;    // bf16 N*64
  constexpr size_t OFF_NEWE  = OFF_XAN   + 1280000;    // f32 N
  constexpr size_t OFF_PART  = OFF_NEWE  + 40000;      // f32 128*4096
  constexpr size_t OFF_BT    = OFF_PART  + 2097152;    // bf16 64*128
  constexpr size_t OFF_W1T   = OFF_BT    + 16384;      // bf16 128*512
  constexpr size_t OFF_W2T   = OFF_W1T   + 131072;     // bf16 64*128
  constexpr size_t OFF_QKVT  = OFF_W2T   + 16384;      // bf16 320*64
  constexpr size_t OFF_BQKV  = OFF_QKVT  + 40960;      // f32 320
  constexpr size_t OFF_FREQS = OFF_BQKV  + 1280;       // f32 16
  constexpr size_t OFF_LAM   = OFF_FREQS + 64;         // f32 1
  constexpr size_t WS_NEED   = OFF_LAM   + 64;
  if (ws_size < WS_NEED) return;

  char* ws = (char*)d_ws;
  float* h_buf   = (float*)(ws + OFF_H);
  bf16*  t1b     = (bf16*)(ws + OFF_T1B);
  bf16*  hT      = (bf16*)(ws + OFF_HT);
  bf16*  mh      = (bf16*)(ws + OFF_MH);
  bf16*  qq      = (bf16*)(ws + OFF_QQ);
  bf16*  kv      = (bf16*)(ws + OFF_KV);
  bf16*  wutxT   = (bf16*)(ws + OFF_WUTXT);
  float* h_fur   = (float*)(ws + OFF_HFUR);
  bf16*  xan     = (bf16*)(ws + OFF_XAN);
  float* newe    = (float*)(ws + OFF_NEWE);
  float* part    = (float*)(ws + OFF_PART);
  bf16*  Bt      = (bf16*)(ws + OFF_BT);
  bf16*  w1T     = (bf16*)(ws + OFF_W1T);
  bf16*  w2T     = (bf16*)(ws + OFF_W2T);
  bf16*  qkvT    = (bf16*)(ws + OFF_QKVT);
  float* bqkv    = (float*)(ws + OFF_BQKV);
  float* freqs   = (float*)(ws + OFF_FREQS);
  float* lamb    = (float*)(ws + OFF_LAM);

  prep_kernel<<<64, 256, 0, stream>>>(fe_w1, fe_w2, wq1, wk1, wq2, wk2, wv_in,
                                      bq1, bk1, bq2, bk2, bv_in,
                                      lq1, lk1, lq2, lk2, freq_deltas, freq_bias,
                                      w1T, w2T, qkvT, bqkv, freqs, lamb);
  newe_kernel<<<40, 256, 0, stream>>>(e, readout_w, readout_b, alpha_w, freqs, newe);
  g1_kernel<<<157, 256, 0, stream>>>(x, w1T, fe_b1, t1b);
  g2_kernel<<<157, 256, 0, stream>>>(t1b, w2T, fe_b2, h_buf, hT);
  mhln_kernel<<<2500, 256, 0, stream>>>(h_buf, mha_ln_g, mha_ln_b, mh);
  qkv_kernel<<<157, 256, 0, stream>>>(mh, qkvT, bqkv, qq, kv);
  r1_kernel<<<64, 256, 0, stream>>>(kv, part);
  r2_kernel<<<32, 256, 0, stream>>>(part, lamb, Bt);
  d_kernel<<<313, 256, 0, stream>>>(u, hT, newe, wutxT);
  e_kernel<<<313, 256, 0, stream>>>(u, wutxT, h_fur);
  hattn_kernel<<<157, 256, 0, stream>>>(qq, Bt, attn_ln_g, attn_ln_b, xan);
  final_kernel<<<2500, 256, 0, stream>>>(h_buf, h_fur, xan, out_w, out_b,
                                         gate_ln_g, gate_ln_b, gate_w, gate_b,
                                         ffn_ln_g, ffn_ln_b, ffn_w1, ffn_b1, ffn_w2, ffn_b2,
                                         (float*)d_out);
}

// Round 2
// 353.021 us; speedup vs baseline: 1.7827x; 1.7827x over previous
//
#include <hip/hip_runtime.h>
#include <hip/hip_bf16.h>
#include <math.h>

#define NN 10000
#define J48 10048
#define CHUNKS 157
#define CPS 20
#define SPLITS 8

typedef __bf16 bf16;
typedef bf16 bf16x8 __attribute__((ext_vector_type(8)));
typedef float f32x4 __attribute__((ext_vector_type(4)));

__device__ __forceinline__ float wave_sum64(float v) {
#pragma unroll
  for (int m = 32; m >= 1; m >>= 1) v += __shfl_xor(v, m, 64);
  return v;
}

// ---------------------------------------------------------------- prep
__global__ void prep_kernel(const float* __restrict__ w1, const float* __restrict__ w2,
                            const float* __restrict__ wq1, const float* __restrict__ wk1,
                            const float* __restrict__ wq2, const float* __restrict__ wk2,
                            const float* __restrict__ wvw,
                            const float* __restrict__ bq1, const float* __restrict__ bk1,
                            const float* __restrict__ bq2, const float* __restrict__ bk2,
                            const float* __restrict__ bvv,
                            const float* __restrict__ lq1, const float* __restrict__ lk1,
                            const float* __restrict__ lq2, const float* __restrict__ lk2,
                            const float* __restrict__ freq_deltas, const float* __restrict__ freq_bias,
                            bf16* __restrict__ w1T, bf16* __restrict__ w2T, bf16* __restrict__ qkvT,
                            float* __restrict__ bqkv, float* __restrict__ freqs, float* __restrict__ lamb) {
  int tid = blockIdx.x * blockDim.x + threadIdx.x;
  int nthr = gridDim.x * blockDim.x;
  for (int i = tid; i < 512 * 128; i += nthr) {
    int o = i >> 9, k = i & 511;
    w1T[i] = (bf16)w1[k * 128 + o];
  }
  for (int i = tid; i < 64 * 128; i += nthr) {
    int o = i >> 7, k = i & 127;
    w2T[i] = (bf16)w2[k * 64 + o];
  }
  for (int i = tid; i < 320 * 64; i += nthr) {
    int r = i >> 6, k = i & 63;
    const float* W = (r < 64) ? wq1 : (r < 128) ? wk1 : (r < 192) ? wq2 : (r < 256) ? wk2 : wvw;
    qkvT[i] = (bf16)W[k * 64 + (r & 63)];
  }
  for (int i = tid; i < 320; i += nthr) {
    const float* B = (i < 64) ? bq1 : (i < 128) ? bk1 : (i < 192) ? bq2 : (i < 256) ? bk2 : bvv;
    bqkv[i] = B[i & 63];
  }
  if (blockIdx.x == 0) {
    if (threadIdx.x == 0) {
      float acc = freq_bias[0];
      for (int f = 0; f < 16; f++) {
        acc += log1pf(expf(freq_deltas[f])) + 0.25f;
        freqs[f] = 50.0f * tanhf(acc * (1.0f / 50.0f));
      }
    }
    if (threadIdx.x >= 64 && threadIdx.x < 128) {
      int l = threadIdx.x - 64;
      float s1 = wave_sum64(lq1[l] * lk1[l]);
      float s2 = wave_sum64(lq2[l] * lk2[l]);
      if (l == 0) lamb[0] = expf(s1) - expf(s2) + 0.2f;
    }
  }
}

// ---------------------------------------------------------------- new_e
__global__ void newe_kernel(const float* __restrict__ e, const float* __restrict__ rw,
                            const float* __restrict__ rb, const float* __restrict__ aw,
                            const float* __restrict__ freqs, float* __restrict__ newe) {
  int n = blockIdx.x * blockDim.x + threadIdx.x;
  if (n >= NN) return;
  float fr[16];
#pragma unroll
  for (int f = 0; f < 16; f++) fr[f] = freqs[f];
  float ev = e[n], p = 1.0f, acc = 0.0f;
  for (int k = 0; k < 10; k++) {
    p *= ev;
    float s = rb[k] + rw[k * 33];
#pragma unroll
    for (int f = 0; f < 16; f++) {
      float ph = p * fr[f];
      s += 0.25f * (__sinf(ph) * rw[k * 33 + 1 + f] + __cosf(ph) * rw[k * 33 + 17 + f]);
    }
    acc += s * aw[k];
  }
  newe[n] = acc;
}

// ---------------------------------------------------------------- G1
__global__ __launch_bounds__(256) void g1_kernel(const float* __restrict__ x, const bf16* __restrict__ w1T,
                                                 const float* __restrict__ b1, bf16* __restrict__ t1b) {
  __shared__ bf16 la[64][40];
  __shared__ bf16 lb[128][40];
  const int bm = blockIdx.x * 64;
  const int lane = threadIdx.x & 63, wvid = threadIdx.x >> 6;
  const int am = threadIdx.x >> 2, aseg = (threadIdx.x & 3) * 8;
  const int arow = bm + am;
  f32x4 acc[8] = {};
  float4 aLo, aHi;
  uint4 bChunk[2];
  auto fetchAll = [&](int k0) {
    if (arow < NN) {
      const float4* p = (const float4*)(x + (size_t)arow * 512 + k0 + aseg);
      aLo = p[0]; aHi = p[1];
    } else {
      aLo = make_float4(0.f, 0.f, 0.f, 0.f); aHi = aLo;
    }
#pragma unroll
    for (int r = 0; r < 2; r++) {
      int slot = threadIdx.x * 2 + r;
      int n = slot >> 2, seg = (slot & 3) * 8;
      bChunk[r] = *(const uint4*)(w1T + n * 512 + k0 + seg);
    }
  };
  auto store = [&]() {
    union { uint4 v; bf16 b[8]; } pk;
    float av[8] = {aLo.x, aLo.y, aLo.z, aLo.w, aHi.x, aHi.y, aHi.z, aHi.w};
#pragma unroll
    for (int t = 0; t < 8; t++) pk.b[t] = (bf16)av[t];
    *(uint4*)&la[am][aseg] = pk.v;
#pragma unroll
    for (int r = 0; r < 2; r++) {
      int slot = threadIdx.x * 2 + r;
      int n = slot >> 2, seg = (slot & 3) * 8;
      *(uint4*)&lb[n][seg] = bChunk[r];
    }
  };
  fetchAll(0);
  for (int k0 = 0; k0 < 512; k0 += 32) {
    store();
    if (k0 + 32 < 512) fetchAll(k0 + 32);
    __syncthreads();
    bf16x8 af = *(const bf16x8*)&la[wvid * 16 + (lane & 15)][(lane >> 4) * 8];
#pragma unroll
    for (int s = 0; s < 8; s++) {
      bf16x8 bfr = *(const bf16x8*)&lb[s * 16 + (lane & 15)][(lane >> 4) * 8];
      acc[s] = __builtin_amdgcn_mfma_f32_16x16x32_bf16(af, bfr, acc[s], 0, 0, 0);
    }
    __syncthreads();
  }
#pragma unroll
  for (int s = 0; s < 8; s++) {
    int col = s * 16 + (lane & 15);
    float bvv = b1[col];
#pragma unroll
    for (int r = 0; r < 4; r++) {
      int row = bm + wvid * 16 + (lane >> 4) * 4 + r;
      if (row < NN) {
        float v = acc[s][r] + bvv;
        t1b[(size_t)row * 128 + col] = (bf16)(v > 0.f ? v : 0.f);
      }
    }
  }
}

// ---------------------------------------------------------------- G2
__global__ __launch_bounds__(256) void g2_kernel(const bf16* __restrict__ t1b, const bf16* __restrict__ w2T,
                                                 const float* __restrict__ b2, float* __restrict__ h,
                                                 bf16* __restrict__ hT) {
  __shared__ bf16 la[64][72];
  __shared__ bf16 lb[64][72];
  const int bm = blockIdx.x * 64;
  const int lane = threadIdx.x & 63, wvid = threadIdx.x >> 6;
  f32x4 acc[4] = {};
  for (int k0 = 0; k0 < 128; k0 += 64) {
#pragma unroll
    for (int r = 0; r < 2; r++) {
      int slot = threadIdx.x * 2 + r;
      int m = slot >> 3, seg = (slot & 7) * 8;
      int row = bm + m;
      uint4 val = make_uint4(0u, 0u, 0u, 0u);
      if (row < NN) val = *(const uint4*)(t1b + (size_t)row * 128 + k0 + seg);
      *(uint4*)&la[m][seg] = val;
      *(uint4*)&lb[m][seg] = *(const uint4*)(w2T + m * 128 + k0 + seg);
    }
    __syncthreads();
#pragma unroll
    for (int ks = 0; ks < 2; ks++) {
      bf16x8 af = *(const bf16x8*)&la[wvid * 16 + (lane & 15)][ks * 32 + (lane >> 4) * 8];
#pragma unroll
      for (int s = 0; s < 4; s++) {
        bf16x8 bfr = *(const bf16x8*)&lb[s * 16 + (lane & 15)][ks * 32 + (lane >> 4) * 8];
        acc[s] = __builtin_amdgcn_mfma_f32_16x16x32_bf16(af, bfr, acc[s], 0, 0, 0);
      }
    }
    __syncthreads();
  }
#pragma unroll
  for (int s = 0; s < 4; s++) {
    int col = s * 16 + (lane & 15);
    float bvv = b2[col];
#pragma unroll
    for (int r = 0; r < 4; r++) {
      int row = bm + wvid * 16 + (lane >> 4) * 4 + r;
      if (row < NN) {
        float v = acc[s][r] + bvv;
        h[(size_t)row * 64 + col] = v;
        hT[(size_t)col * NN + row] = (bf16)v;
      }
    }
  }
}

// ---------------------------------------------------------------- mh = LN(h)
__global__ __launch_bounds__(256) void mhln_kernel(const float* __restrict__ h, const float* __restrict__ g,
                                                   const float* __restrict__ b, bf16* __restrict__ mh) {
  int row = blockIdx.x * 4 + (threadIdx.x >> 6);
  int lane = threadIdx.x & 63;
  if (row >= NN) return;
  float v = h[(size_t)row * 64 + lane];
  float m = wave_sum64(v) * (1.0f / 64.0f);
  float d = v - m;
  float var = wave_sum64(d * d) * (1.0f / 64.0f);
  mh[(size_t)row * 64 + lane] = (bf16)(g[lane] * d * rsqrtf(var + 1e-5f) + b[lane]);
}

// ---------------------------------------------------------------- QKV
__global__ __launch_bounds__(256) void qkv_kernel(const bf16* __restrict__ mh, const bf16* __restrict__ qkvT,
                                                  const float* __restrict__ bqkv,
                                                  bf16* __restrict__ qq, bf16* __restrict__ kv) {
  __shared__ bf16 la[64][72];
  __shared__ bf16 lb[320][72];
  const int bm = blockIdx.x * 64;
  const int lane = threadIdx.x & 63, wvid = threadIdx.x >> 6;
#pragma unroll
  for (int r = 0; r < 2; r++) {
    int slot = threadIdx.x * 2 + r;
    int m = slot >> 3, seg = (slot & 7) * 8;
    int row = bm + m;
    uint4 val = make_uint4(0u, 0u, 0u, 0u);
    if (row < NN) val = *(const uint4*)(mh + (size_t)row * 64 + seg);
    *(uint4*)&la[m][seg] = val;
  }
#pragma unroll
  for (int r = 0; r < 10; r++) {
    int slot = threadIdx.x * 10 + r;
    int n = slot >> 3, seg = (slot & 7) * 8;
    *(uint4*)&lb[n][seg] = *(const uint4*)(qkvT + n * 64 + seg);
  }
  __syncthreads();
  f32x4 acc[20] = {};
#pragma unroll
  for (int ks = 0; ks < 2; ks++) {
    bf16x8 af = *(const bf16x8*)&la[wvid * 16 + (lane & 15)][ks * 32 + (lane >> 4) * 8];
#pragma unroll
    for (int s = 0; s < 20; s++) {
      bf16x8 bfr = *(const bf16x8*)&lb[s * 16 + (lane & 15)][ks * 32 + (lane >> 4) * 8];
      acc[s] = __builtin_amdgcn_mfma_f32_16x16x32_bf16(af, bfr, acc[s], 0, 0, 0);
    }
  }
#pragma unroll
  for (int s = 0; s < 20; s++) {
    int col = s * 16 + (lane & 15);
    float bvv = bqkv[col];
    bf16* dst; int dc, stride;
    if (col < 64)       { dst = qq; dc = col;       stride = 128; }
    else if (col < 128) { dst = kv; dc = col - 64;  stride = 192; }
    else if (col < 192) { dst = qq; dc = col - 64;  stride = 128; }
    else                { dst = kv; dc = col - 128; stride = 192; }
#pragma unroll
    for (int r = 0; r < 4; r++) {
      int row = bm + wvid * 16 + (lane >> 4) * 4 + r;
      if (row < NN) dst[(size_t)row * stride + dc] = (bf16)(acc[s][r] + bvv);
    }
  }
}

// ---------------------------------------------------------------- R1: partial k1^T v, k2^T v (250 blocks, contiguous rows)
__global__ __launch_bounds__(256) void r1_kernel(const bf16* __restrict__ kv, float* __restrict__ part) {
  int b = blockIdx.x;            // 0..249, rows b*40 .. b*40+39
  int c1 = threadIdx.x & 63, grp = threadIdx.x >> 6;
  int r0 = b * 40;
  float a1[16] = {}, a2[16] = {};
  for (int r = 0; r < 40; r++) {
    const bf16* rowp = kv + (size_t)(r0 + r) * 192;
    float k1 = (float)rowp[c1];
    float k2 = (float)rowp[64 + c1];
#pragma unroll
    for (int q = 0; q < 16; q++) {
      float vv = (float)rowp[128 + grp * 16 + q];
      a1[q] += k1 * vv; a2[q] += k2 * vv;
    }
  }
  float* p1 = part + ((size_t)(b * 2 + 0) * 64 + c1) * 64 + grp * 16;
  float* p2 = part + ((size_t)(b * 2 + 1) * 64 + c1) * 64 + grp * 16;
#pragma unroll
  for (int q = 0; q < 16; q++) { p1[q] = a1[q]; p2[q] = a2[q]; }
}

// ---------------------------------------------------------------- R2
__global__ void r2_kernel(const float* __restrict__ part, const float* __restrict__ lamb, bf16* __restrict__ Bt) {
  int idx = blockIdx.x * 256 + threadIdx.x;
  int mat = idx >> 12, rem = idx & 4095;
  int d = rem >> 6, c = rem & 63;
  float s = 0.f;
  for (int b = 0; b < 250; b++) s += part[(size_t)(b * 2 + mat) * 4096 + rem];
  float v = mat ? (-lamb[0] * s) : s;
  Bt[c * 128 + mat * 64 + d] = (bf16)v;
}

// ---------------------------------------------------------------- D split-K: dpart[sk][c][j] = sum_{i in split} h[i,c]*u[i,j]
__global__ __launch_bounds__(256) void d_split_kernel(const float* __restrict__ u, const bf16* __restrict__ hT,
                                                      float* __restrict__ dpart) {
  __shared__ bf16 la[64][72];   // hT tile [c][i]
  __shared__ bf16 lb[64][72];   // u^T tile [j][i], XOR-swizzled in i
  const int j0 = blockIdx.x * 64;
  const int sk = blockIdx.y;
  const int c0 = sk * CPS, c1e = min(CHUNKS, c0 + CPS);
  const int t = threadIdx.x;
  const int lane = t & 63, wv = t >> 6;
  const int jl = (t & 15) * 4;
  const int ir = (t >> 4) * 4;
  f32x4 acc[4] = {};
  uint4 aC[2];
  float4 bC[4];
  auto fetchAll = [&](int i0) {
#pragma unroll
    for (int r = 0; r < 2; r++) {
      int slot = t * 2 + r;
      int c = slot >> 3, seg = (slot & 7) * 8;
      int i = i0 + seg;
      if (i + 7 < NN) aC[r] = *(const uint4*)(hT + (size_t)c * NN + i);
      else {
        union { uint4 v; bf16 b[8]; } tu;
#pragma unroll
        for (int q = 0; q < 8; q++) tu.b[q] = (i + q < NN) ? hT[(size_t)c * NN + i + q] : (bf16)0.f;
        aC[r] = tu.v;
      }
    }
#pragma unroll
    for (int q = 0; q < 4; q++) {
      int i = i0 + ir + q;
      if (i < NN && (j0 + jl + 3) < NN) bC[q] = *(const float4*)(u + (size_t)i * NN + j0 + jl);
      else if (i < NN) {
        float tmp[4];
#pragma unroll
        for (int q2 = 0; q2 < 4; q2++) tmp[q2] = (j0 + jl + q2 < NN) ? u[(size_t)i * NN + j0 + jl + q2] : 0.f;
        bC[q] = make_float4(tmp[0], tmp[1], tmp[2], tmp[3]);
      } else bC[q] = make_float4(0.f, 0.f, 0.f, 0.f);
    }
  };
  auto storeAll = [&]() {
#pragma unroll
    for (int r = 0; r < 2; r++) {
      int slot = t * 2 + r;
      int c = slot >> 3, seg = (slot & 7) * 8;
      *(uint4*)&la[c][seg] = aC[r];
    }
#pragma unroll
    for (int q2 = 0; q2 < 4; q2++) {
      int j = jl + q2;
      int isw = ir ^ (((j >> 2) & 3) << 3);
      union { uint2 w; bf16 b[4]; } pk;
      pk.b[0] = (bf16)((float*)&bC[0])[q2];
      pk.b[1] = (bf16)((float*)&bC[1])[q2];
      pk.b[2] = (bf16)((float*)&bC[2])[q2];
      pk.b[3] = (bf16)((float*)&bC[3])[q2];
      *(uint2*)&lb[j][isw] = pk.w;
    }
  };
  fetchAll(c0 * 64);
  for (int ch = c0; ch < c1e; ch++) {
    storeAll();
    if (ch + 1 < c1e) fetchAll((ch + 1) * 64);
    __syncthreads();
#pragma unroll
    for (int ks = 0; ks < 2; ks++) {
      bf16x8 af = *(const bf16x8*)&la[wv * 16 + (lane & 15)][ks * 32 + (lane >> 4) * 8];
#pragma unroll
      for (int s = 0; s < 4; s++) {
        int j = s * 16 + (lane & 15);
        int ioff = (ks * 32 + (lane >> 4) * 8) ^ (((j >> 2) & 3) << 3);
        bf16x8 bfr = *(const bf16x8*)&lb[j][ioff];
        acc[s] = __builtin_amdgcn_mfma_f32_16x16x32_bf16(af, bfr, acc[s], 0, 0, 0);
      }
    }
    __syncthreads();
  }
#pragma unroll
  for (int s = 0; s < 4; s++) {
    int col = s * 16 + (lane & 15);
#pragma unroll
    for (int r = 0; r < 4; r++) {
      int c = wv * 16 + (lane >> 4) * 4 + r;
      dpart[((size_t)sk * 64 + c) * J48 + j0 + col] = acc[s][r];
    }
  }
}

// ---------------------------------------------------------------- D reduce: wutxT[c][j] = bf16(newe[j] * sum_s dpart)
__global__ void dred_kernel(const float* __restrict__ dpart, const float* __restrict__ newe,
                            bf16* __restrict__ wutxT) {
  int idx = blockIdx.x * 256 + threadIdx.x;
  int c = idx / 2512;
  int j = (idx - c * 2512) * 4;
  if (c >= 64 || j >= NN) return;
  f32x4 s = {};
  for (int sk = 0; sk < SPLITS; sk++)
    s += *(const f32x4*)(dpart + ((size_t)sk * 64 + c) * J48 + j);
  union { uint2 w; bf16 b[4]; } pk;
#pragma unroll
  for (int q = 0; q < 4; q++) pk.b[q] = (bf16)(newe[j + q] * s[q]);
  *(uint2*)&wutxT[(size_t)c * NN + j] = pk.w;
}

// ---------------------------------------------------------------- E split-K: epart[sk][i][c] = sum_{j in split} u[i,j]*wutx[j,c]
__global__ __launch_bounds__(256) void e_split_kernel(const float* __restrict__ u, const bf16* __restrict__ wutxT,
                                                      float* __restrict__ epart) {
  __shared__ bf16 la[64][72];   // u rows bf16 [i_local][j]
  __shared__ bf16 lb[64][72];   // wutxT [c][j]
  const int bm = blockIdx.x * 64;
  const int sk = blockIdx.y;
  const int c0 = sk * CPS, c1e = min(CHUNKS, c0 + CPS);
  const int t = threadIdx.x;
  const int lane = t & 63, wv = t >> 6;
  const int mA = t >> 2, segA = (t & 3) * 16;
  const int mrow = bm + mA;
  f32x4 acc[4] = {};
  float4 aC[4];
  uint4 bC[2];
  auto fetchAll = [&](int j0) {
    int j = j0 + segA;
    if (mrow < NN && j + 15 < NN) {
      const float4* p = (const float4*)(u + (size_t)mrow * NN + j);
      aC[0] = p[0]; aC[1] = p[1]; aC[2] = p[2]; aC[3] = p[3];
    } else {
#pragma unroll
      for (int q = 0; q < 4; q++) {
        float tmp[4];
#pragma unroll
        for (int q2 = 0; q2 < 4; q2++) {
          int jj = j + q * 4 + q2;
          tmp[q2] = (mrow < NN && jj < NN) ? u[(size_t)mrow * NN + jj] : 0.f;
        }
        aC[q] = make_float4(tmp[0], tmp[1], tmp[2], tmp[3]);
      }
    }
#pragma unroll
    for (int r = 0; r < 2; r++) {
      int slot = t * 2 + r;
      int c = slot >> 3, seg = (slot & 7) * 8;
      int jj = j0 + seg;
      if (jj + 7 < NN) bC[r] = *(const uint4*)(wutxT + (size_t)c * NN + jj);
      else {
        union { uint4 v; bf16 b[8]; } tu;
#pragma unroll
        for (int q = 0; q < 8; q++) tu.b[q] = (jj + q < NN) ? wutxT[(size_t)c * NN + jj + q] : (bf16)0.f;
        bC[r] = tu.v;
      }
    }
  };
  auto storeAll = [&]() {
    union { uint4 v[2]; bf16 b[16]; } pk;
#pragma unroll
    for (int q = 0; q < 4; q++)
#pragma unroll
      for (int q2 = 0; q2 < 4; q2++) pk.b[q * 4 + q2] = (bf16)((float*)&aC[q])[q2];
    *(uint4*)&la[mA][segA] = pk.v[0];
    *(uint4*)&la[mA][segA + 8] = pk.v[1];
#pragma unroll
    for (int r = 0; r < 2; r++) {
      int slot = t * 2 + r;
      int c = slot >> 3, seg = (slot & 7) * 8;
      *(uint4*)&lb[c][seg] = bC[r];
    }
  };
  fetchAll(c0 * 64);
  for (int ch = c0; ch < c1e; ch++) {
    storeAll();
    if (ch + 1 < c1e) fetchAll((ch + 1) * 64);
    __syncthreads();
#pragma unroll
    for (int ks = 0; ks < 2; ks++) {
      bf16x8 af = *(const bf16x8*)&la[wv * 16 + (lane & 15)][ks * 32 + (lane >> 4) * 8];
#pragma unroll
      for (int s = 0; s < 4; s++) {
        bf16x8 bfr = *(const bf16x8*)&lb[s * 16 + (lane & 15)][ks * 32 + (lane >> 4) * 8];
        acc[s] = __builtin_amdgcn_mfma_f32_16x16x32_bf16(af, bfr, acc[s], 0, 0, 0);
      }
    }
    __syncthreads();
  }
#pragma unroll
  for (int s = 0; s < 4; s++) {
    int col = s * 16 + (lane & 15);
#pragma unroll
    for (int r = 0; r < 4; r++) {
      int row = wv * 16 + (lane >> 4) * 4 + r;
      epart[((size_t)sk * J48 + bm + row) * 64 + col] = acc[s][r];
    }
  }
}

// ---------------------------------------------------------------- E reduce
__global__ void ered_kernel(const float* __restrict__ epart, float* __restrict__ h_fur) {
  int idx = blockIdx.x * 256 + threadIdx.x;
  if (idx >= NN * 16) return;
  size_t off = (size_t)idx * 4;
  f32x4 s = {};
  for (int sk = 0; sk < SPLITS; sk++)
    s += *(const f32x4*)(epart + (size_t)sk * (J48 * 64) + off);
  *(f32x4*)(h_fur + off) = s;
}

// ---------------------------------------------------------------- H: xa = qq@Bt ; LN ; *0.8
__global__ __launch_bounds__(256) void hattn_kernel(const bf16* __restrict__ qq, const bf16* __restrict__ Bt,
                                                    const float* __restrict__ g, const float* __restrict__ b,
                                                    bf16* __restrict__ xan) {
  __shared__ bf16 la[64][136];
  __shared__ bf16 lb[64][136];
  const int bm = blockIdx.x * 64;
  const int lane = threadIdx.x & 63, wvid = threadIdx.x >> 6;
#pragma unroll
  for (int r = 0; r < 4; r++) {
    int slot = threadIdx.x * 4 + r;
    int m = slot >> 4, seg = (slot & 15) * 8;
    int row = bm + m;
    uint4 val = make_uint4(0u, 0u, 0u, 0u);
    if (row < NN) val = *(const uint4*)(qq + (size_t)row * 128 + seg);
    *(uint4*)&la[m][seg] = val;
    *(uint4*)&lb[m][seg] = *(const uint4*)(Bt + m * 128 + seg);
  }
  __syncthreads();
  f32x4 acc[4] = {};
#pragma unroll
  for (int ks = 0; ks < 4; ks++) {
    bf16x8 af = *(const bf16x8*)&la[wvid * 16 + (lane & 15)][ks * 32 + (lane >> 4) * 8];
#pragma unroll
    for (int s = 0; s < 4; s++) {
      bf16x8 bfr = *(const bf16x8*)&lb[s * 16 + (lane & 15)][ks * 32 + (lane >> 4) * 8];
      acc[s] = __builtin_amdgcn_mfma_f32_16x16x32_bf16(af, bfr, acc[s], 0, 0, 0);
    }
  }
#pragma unroll
  for (int r = 0; r < 4; r++) {
    float psum = acc[0][r] + acc[1][r] + acc[2][r] + acc[3][r];
#pragma unroll
    for (int msk = 1; msk < 16; msk <<= 1) psum += __shfl_xor(psum, msk, 64);
    float mean = psum * (1.0f / 64.0f);
    float pvar = 0.f;
#pragma unroll
    for (int s = 0; s < 4; s++) { float dd = acc[s][r] - mean; pvar += dd * dd; }
#pragma unroll
    for (int msk = 1; msk < 16; msk <<= 1) pvar += __shfl_xor(pvar, msk, 64);
    float rsq = rsqrtf(pvar * (1.0f / 64.0f) + 1e-5f);
    int row = bm + wvid * 16 + (lane >> 4) * 4 + r;
    if (row < NN) {
#pragma unroll
      for (int s = 0; s < 4; s++) {
        int col = s * 16 + (lane & 15);
        float o = 0.8f * (g[col] * (acc[s][r] - mean) * rsq + b[col]);
        xan[(size_t)row * 64 + col] = (bf16)o;
      }
    }
  }
}

// ---------------------------------------------------------------- final
__global__ __launch_bounds__(256) void final_kernel(const float* __restrict__ h, const float* __restrict__ h_fur,
                                                    const bf16* __restrict__ xan,
                                                    const float* __restrict__ out_w, const float* __restrict__ out_b,
                                                    const float* __restrict__ gg, const float* __restrict__ gb,
                                                    const float* __restrict__ gw, const float* __restrict__ gbias,
                                                    const float* __restrict__ fg, const float* __restrict__ fb,
                                                    const float* __restrict__ fw1, const float* __restrict__ fb1,
                                                    const float* __restrict__ fw2, const float* __restrict__ fb2,
                                                    float* __restrict__ out) {
  __shared__ float s_ow[64][64];
  __shared__ float s_w1[64][64];
  __shared__ float s_w2[64][64];
  __shared__ float s_gw[192][3];
  __shared__ float s_row[4][64];
  const int lane = threadIdx.x & 63, wvid = threadIdx.x >> 6;
  for (int i = threadIdx.x; i < 4096; i += 256) {
    ((float*)s_ow)[i] = out_w[i];
    ((float*)s_w1)[i] = fw1[i];
    ((float*)s_w2)[i] = fw2[i];
  }
  for (int i = threadIdx.x; i < 576; i += 256) ((float*)s_gw)[i] = gw[i];
  const int row = blockIdx.x * 4 + wvid;
  float x_h = h[(size_t)row * 64 + lane];
  float x_f = h_fur[(size_t)row * 64 + lane];
  float x_a = (float)xan[(size_t)row * 64 + lane];
  s_row[wvid][lane] = x_a;
  __syncthreads();
  float mha = out_b[lane];
#pragma unroll 8
  for (int d = 0; d < 64; d++) mha += s_row[wvid][d] * s_ow[d][lane];
  float m3 = wave_sum64(x_h + mha + x_f) * (1.0f / 192.0f);
  float dh = x_h - m3, dm = mha - m3, df = x_f - m3;
  float v3 = wave_sum64(dh * dh + dm * dm + df * df) * (1.0f / 192.0f);
  float rs3 = rsqrtf(v3 + 1e-5f);
  float l0 = gg[lane] * dh * rs3 + gb[lane];
  float l1 = gg[64 + lane] * dm * rs3 + gb[64 + lane];
  float l2 = gg[128 + lane] * df * rs3 + gb[128 + lane];
  float p0 = l0 * s_gw[lane][0] + l1 * s_gw[64 + lane][0] + l2 * s_gw[128 + lane][0];
  float p1 = l0 * s_gw[lane][1] + l1 * s_gw[64 + lane][1] + l2 * s_gw[128 + lane][1];
  float p2 = l0 * s_gw[lane][2] + l1 * s_gw[64 + lane][2] + l2 * s_gw[128 + lane][2];
  p0 = wave_sum64(p0) + gbias[0];
  p1 = wave_sum64(p1) + gbias[1];
  p2 = wave_sum64(p2) + gbias[2];
  float mx = fmaxf(p0, fmaxf(p1, p2));
  float e0 = expf(p0 - mx), e1 = expf(p1 - mx), e2 = expf(p2 - mx);
  float inv = 1.0f / (e0 + e1 + e2);
  float mix = x_h * (e0 * inv) + mha * (e1 * inv) + x_f * (e2 * inv);
  float mf = wave_sum64(mix) * (1.0f / 64.0f);
  float dmx = mix - mf;
  float vf = wave_sum64(dmx * dmx) * (1.0f / 64.0f);
  float f = fg[lane] * dmx * rsqrtf(vf + 1e-5f) + fb[lane];
  __syncthreads();
  s_row[wvid][lane] = f;
  __syncthreads();
  float t1 = fb1[lane];
#pragma unroll 8
  for (int d = 0; d < 64; d++) t1 += s_row[wvid][d] * s_w1[d][lane];
  t1 = 0.5f * t1 * (1.0f + erff(t1 * 0.70710678118654752f));
  __syncthreads();
  s_row[wvid][lane] = t1;
  __syncthreads();
  float f2 = fb2[lane];
#pragma unroll 8
  for (int d = 0; d < 64; d++) f2 += s_row[wvid][d] * s_w2[d][lane];
  out[(size_t)row * 64 + lane] = mix + f2;
}

// ================================================================ launch
extern "C" void kernel_launch(void* const* d_in, const int* in_sizes, int n_in,
                              void* d_out, int out_size, void* d_ws, size_t ws_size,
                              hipStream_t stream) {
  const float* e          = (const float*)d_in[0];
  const float* u          = (const float*)d_in[1];
  const float* x          = (const float*)d_in[2];
  const float* fe_w1      = (const float*)d_in[3];
  const float* fe_b1      = (const float*)d_in[4];
  const float* fe_w2      = (const float*)d_in[5];
  const float* fe_b2      = (const float*)d_in[6];
  const float* freq_deltas= (const float*)d_in[7];
  const float* freq_bias  = (const float*)d_in[8];
  const float* readout_w  = (const float*)d_in[9];
  const float* readout_b  = (const float*)d_in[10];
  const float* alpha_w    = (const float*)d_in[11];
  const float* mha_ln_g   = (const float*)d_in[12];
  const float* mha_ln_b   = (const float*)d_in[13];
  const float* wq1        = (const float*)d_in[14];
  const float* bq1        = (const float*)d_in[15];
  const float* wk1        = (const float*)d_in[16];
  const float* bk1        = (const float*)d_in[17];
  const float* wq2        = (const float*)d_in[18];
  const float* bq2        = (const float*)d_in[19];
  const float* wk2        = (const float*)d_in[20];
  const float* bk2        = (const float*)d_in[21];
  const float* wv_in      = (const float*)d_in[22];
  const float* bv_in      = (const float*)d_in[23];
  const float* lq1        = (const float*)d_in[24];
  const float* lk1        = (const float*)d_in[25];
  const float* lq2        = (const float*)d_in[26];
  const float* lk2        = (const float*)d_in[27];
  const float* attn_ln_g  = (const float*)d_in[28];
  const float* attn_ln_b  = (const float*)d_in[29];
  const float* out_w      = (const float*)d_in[30];
  const float* out_b      = (const float*)d_in[31];
  const float* gate_ln_g  = (const float*)d_in[32];
  const float* gate_ln_b  = (const float*)d_in[33];
  const float* gate_w     = (const float*)d_in[34];
  const float* gate_b     = (const float*)d_in[35];
  const float* ffn_ln_g   = (const float*)d_in[36];
  const float* ffn_ln_b   = (const float*)d_in[37];
  const float* ffn_w1     = (const float*)d_in[38];
  const float* ffn_b1     = (const float*)d_in[39];
  const float* ffn_w2     = (const float*)d_in[40];
  const float* ffn_b2     = (const float*)d_in[41];

  constexpr size_t OFF_H     = 0;               // f32 N*64
  constexpr size_t OFF_T1B   = 2560000;         // bf16 N*128
  constexpr size_t OFF_HT    = 5120000;         // bf16 64*N
  constexpr size_t OFF_MH    = 6400000;         // bf16 N*64
  constexpr size_t OFF_QQ    = 7680000;         // bf16 N*128
  constexpr size_t OFF_KV    = 10240000;        // bf16 N*192
  constexpr size_t OFF_WUTXT = 14080000;        // bf16 64*N
  constexpr size_t OFF_HFUR  = 15360000;        // f32 N*64
  constexpr size_t OFF_XAN   = 17920000;        // bf16 N*64
  constexpr size_t OFF_NEWE  = 19200000;        // f32 N (pad)
  constexpr size_t OFF_BT    = 19240064;        // bf16 64*128
  constexpr size_t OFF_W1T   = 19256448;        // bf16 128*512
  constexpr size_t OFF_W2T   = 19387520;        // bf16 64*128
  constexpr size_t OFF_QKVT  = 19403904;        // bf16 320*64
  constexpr size_t OFF_BQKV  = 19444864;        // f32 320
  constexpr size_t OFF_FREQS = 19446144;        // f32 16
  constexpr size_t OFF_LAM   = 19446208;        // f32 1
  constexpr size_t OFF_BIG   = 19446272;        // shared: r1-part (8.19MB) then d/e partials (20.58MB)
  constexpr size_t WS_NEED   = OFF_BIG + (size_t)SPLITS * J48 * 64 * 4;  // ~40MB
  if (ws_size < WS_NEED) return;

  char* ws = (char*)d_ws;
  float* h_buf   = (float*)(ws + OFF_H);
  bf16*  t1b     = (bf16*)(ws + OFF_T1B);
  bf16*  hT      = (bf16*)(ws + OFF_HT);
  bf16*  mh      = (bf16*)(ws + OFF_MH);
  bf16*  qq      = (bf16*)(ws + OFF_QQ);
  bf16*  kv      = (bf16*)(ws + OFF_KV);
  bf16*  wutxT   = (bf16*)(ws + OFF_WUTXT);
  float* h_fur   = (float*)(ws + OFF_HFUR);
  bf16*  xan     = (bf16*)(ws + OFF_XAN);
  float* newe    = (float*)(ws + OFF_NEWE);
  bf16*  Bt      = (bf16*)(ws + OFF_BT);
  bf16*  w1T     = (bf16*)(ws + OFF_W1T);
  bf16*  w2T     = (bf16*)(ws + OFF_W2T);
  bf16*  qkvT    = (bf16*)(ws + OFF_QKVT);
  float* bqkv    = (float*)(ws + OFF_BQKV);
  float* freqs   = (float*)(ws + OFF_FREQS);
  float* lamb    = (float*)(ws + OFF_LAM);
  float* part    = (float*)(ws + OFF_BIG);      // r1/r2 lifetime
  float* spart   = (float*)(ws + OFF_BIG);      // d/e partials lifetime (disjoint)

  prep_kernel<<<64, 256, 0, stream>>>(fe_w1, fe_w2, wq1, wk1, wq2, wk2, wv_in,
                                      bq1, bk1, bq2, bk2, bv_in,
                                      lq1, lk1, lq2, lk2, freq_deltas, freq_bias,
                                      w1T, w2T, qkvT, bqkv, freqs, lamb);
  newe_kernel<<<40, 256, 0, stream>>>(e, readout_w, readout_b, alpha_w, freqs, newe);
  g1_kernel<<<157, 256, 0, stream>>>(x, w1T, fe_b1, t1b);
  g2_kernel<<<157, 256, 0, stream>>>(t1b, w2T, fe_b2, h_buf, hT);
  mhln_kernel<<<2500, 256, 0, stream>>>(h_buf, mha_ln_g, mha_ln_b, mh);
  qkv_kernel<<<157, 256, 0, stream>>>(mh, qkvT, bqkv, qq, kv);
  r1_kernel<<<250, 256, 0, stream>>>(kv, part);
  r2_kernel<<<32, 256, 0, stream>>>(part, lamb, Bt);
  d_split_kernel<<<dim3(157, SPLITS), 256, 0, stream>>>(u, hT, spart);
  dred_kernel<<<628, 256, 0, stream>>>(spart, newe, wutxT);
  e_split_kernel<<<dim3(157, SPLITS), 256, 0, stream>>>(u, wutxT, spart);
  ered_kernel<<<625, 256, 0, stream>>>(spart, h_fur);
  hattn_kernel<<<157, 256, 0, stream>>>(qq, Bt, attn_ln_g, attn_ln_b, xan);
  final_kernel<<<2500, 256, 0, stream>>>(h_buf, h_fur, xan, out_w, out_b,
                                         gate_ln_g, gate_ln_b, gate_w, gate_b,
                                         ffn_ln_g, ffn_ln_b, ffn_w1, ffn_b1, ffn_w2, ffn_b2,
                                         (float*)d_out);
}